// Round 3
// baseline (214.868 us; speedup 1.0000x reference)
//
#include <hip/hip_runtime.h>
#include <hip/hip_bf16.h>
#include <math.h>

// Problem constants
// B=32, C=64 (Cin==Cout), N=8192, modes F=32, L=20 segments, M=8 Chebyshev
#define NN    8192
#define NROWS 2048      // B*C
#define FF    32
#define LM    160       // L*M

// Workspace layout (float offsets)
// TRIG4 layout: [k4][f][4] : ws[TRIG + (k4*64+f)*4 + j] =
//   f<32 ? cos(2pi f (4k4+j)/N) : sin(2pi (f-32)(4k4+j)/N)
// TRIGT layout: [f][n] row-major (rows 0..31 cos, 32..63 sin) — for k_inv streaming
static constexpr int TRIG   = 0;         // 2048*64*4 = 524288 floats
static constexpr int W1RT   = 524288;    // [f][i][o] 32*64*64
static constexpr int W1IT   = 655360;
static constexpr int GWT    = 786432;    // [i][o] 64*64
static constexpr int AR_    = 790528;    // [160][32]
static constexpr int AI_    = 795648;
static constexpr int WL_    = 800768;    // [160]
static constexpr int WR_    = 800928;
static constexpr int IL_    = 801088;    // int [160]
static constexpr int IR_    = 801248;
static constexpr int XR_    = 801408;    // [2048][32]
static constexpr int XI_    = 866944;
static constexpr int GN_    = 932480;    // [2048][32]
static constexpr int ARAI   = 998016;    // [2048][64]: [0..31]=cos coeff, [32..63]=sin coeff
static constexpr int TRIGT_ = 1129088;   // [64][8192] = 524288 floats
// total = 1653376 floats = 6.31 MB

#define PI_D 3.14159265358979323846

// async global->LDS, 16 bytes per lane (dest must be linear in lane: base + lane*16)
__device__ __forceinline__ void load_lds16(const float* g, float* l) {
  __builtin_amdgcn_global_load_lds(
      (const __attribute__((address_space(1))) void*)g,
      (__attribute__((address_space(3))) void*)l, 16, 0, 0);
}

// ---------------- A1: trig tables (both layouts) ----------------
__global__ __launch_bounds__(256) void k_trig(float* __restrict__ ws) {
  int idx = blockIdx.x * 256 + threadIdx.x;   // 0..524287
  int k4 = idx >> 8, f = (idx >> 2) & 63, j = idx & 3;
  int n = 4 * k4 + j;
  int fr = f & 31;
  int p = (fr * n) & (NN - 1);
  float ang = (float)p * (float)(2.0 * PI_D / (double)NN);
  float s, c;
  sincosf(ang, &s, &c);
  float v = (f < 32) ? c : s;
  ws[TRIG + idx] = v;
  ws[TRIGT_ + f * NN + n] = v;
}

// ---------------- A2: CFT constant tables (double precision, parallel) ----------------
// Chebyshev nodes hardcoded; T_m via recurrence (no acos/cos chain).
__global__ __launch_bounds__(256) void k_cft_tables(float* __restrict__ ws) {
  int tid = blockIdx.x * 256 + threadIdx.x;
  if (tid >= LM * FF) return;
  int j = tid >> 5, f = tid & 31;
  int l = j >> 3, m = j & 7;      // m doubles as Chebyshev order k
  const double cheb[8] = {
    -0.98078528040323044913, -0.83146961230254523708,
    -0.55557023301960222474, -0.19509032201612826785,
     0.19509032201612826785,  0.55557023301960222474,
     0.83146961230254523708,  0.98078528040323044913 };

  double Wr = 0.0, Wi = 0.0;
  #pragma unroll
  for (int mm = 0; mm < 8; ++mm) {
    double c = cheb[mm];
    // T = T_m(c) by recurrence
    double T;
    if (m == 0) T = 1.0;
    else {
      double a = 1.0, b = c;
      for (int q = 1; q < m; ++q) { double t = 2.0 * c * b - a; a = b; b = t; }
      T = b;
    }
    double ang = c * (double)f * (PI_D * 0.05);
    Wr += T * cos(ang);
    Wi += T * (-sin(ang));
  }
  Wr *= 0.025; Wi *= 0.025;
  double phi = 2.0 * PI_D * ((double)l * 0.05) * (double)f;
  double cs = cos(phi), sn = sin(phi);
  ws[AR_ + j * FF + f] = (float)(Wr * cs + Wi * sn);
  ws[AI_ + j * FF + f] = (float)(-Wr * sn + Wi * cs);

  if (f == 0) {
    double v = (double)l * 0.05 + 0.025 * (cheb[m] + 1.0);
    int r = (int)(v * 8191.0);
    while ((double)r / 8191.0 < v) ++r;
    while (r > 0 && (double)(r - 1) / 8191.0 >= v) --r;
    if (r > 8191) r = 8191;
    int le = r - 1; if (le < 0) le = 0;
    double tl = (double)le / 8191.0, tr = (double)r / 8191.0;
    double den = (tr - tl == 0.0) ? 1.0 : (tr - tl);
    double wr = (v - tl) / den;
    ws[WL_ + j] = (float)(1.0 - wr);
    ws[WR_ + j] = (float)wr;
    ((int*)ws)[IL_ + j] = le;
    ((int*)ws)[IR_ + j] = r;
  }
}

// ---------------- A3: transposes ----------------
__global__ __launch_bounds__(256) void k_transpose(const float* __restrict__ w1r,
                                                   const float* __restrict__ w1i,
                                                   const float* __restrict__ gw,
                                                   float* __restrict__ ws) {
  int idx = blockIdx.x * 256 + threadIdx.x;   // 0..131071
  if (idx >= 32 * 64 * 64) return;
  int o = idx & 63, i = (idx >> 6) & 63, f = idx >> 12;   // f in 0..31
  ws[W1RT + (f * 64 + i) * 64 + o] = w1r[(i * 64 + o) * FF + f];
  ws[W1IT + (f * 64 + i) * 64 + o] = w1i[(i * 64 + o) * FF + f];
  if (idx < 4096) {
    ws[GWT + idx] = gw[(idx & 63) * 64 + (idx >> 6)];
  }
}

// ---------------- B1: forward truncated DFT, split-K GEMM ----------------
// Round-0 geometry: grid = 32 row-tiles (64 rows) x 64 K-chunks (128 k), ONE barrier.
// NEW: the 32 KB trig chunk for this kc is staged into LDS next to the 32 KB x tile
// (64 KB/block -> 2 blocks/CU). Both stagings are linear in tid*16 -> global_load_lds,
// zero staging VGPRs. Inner loop addressing is pure immediate-offset ds_read_b128
// from two fixed per-lane base pointers (x: j*512+it*16 <= 4080 B; trig: it*1024(+512)
// <= 32255 B — both fit the 16-bit DS offset). Per iter: 64 FMA + 10 ds_read, no
// address VALU, no 64-bit math. x reads are 2-way broadcast, trig reads half-wave
// mirrored (32 distinct) — zero bank conflicts.
__global__ __launch_bounds__(256) void k_fwd_gemm(const float* __restrict__ x,
                                                  const float* __restrict__ ws,
                                                  float* __restrict__ part) {
  __shared__ __align__(16) float xs[64 * 128];   // 32 KB x tile
  __shared__ __align__(16) float ts[32 * 256];   // 32 KB trig chunk [it][f][4]
  const int rt = blockIdx.x >> 6, kc = blockIdx.x & 63;
  const int t = threadIdx.x;
  const int w = t >> 6, lane = t & 63;
  const int half = lane >> 5, fl = lane & 31;
  const int rblock = rt * 64;
  const int kb = kc * 128;
  const int c4 = t & 31, r0 = t >> 5;            // x staging coords

  // stage x tile: pass p covers float4 indices 256p+t (linear in t -> lds-compatible)
  #pragma unroll
  for (int p = 0; p < 8; ++p) {
    int row = r0 + 8 * p;
    load_lds16(x + (size_t)(rblock + row) * NN + kb + c4 * 4,
               &xs[row * 128 + c4 * 4]);
  }
  // stage trig chunk: contiguous 32 KB starting at TRIG + kc*32*256
  const float* __restrict__ tsrc = ws + TRIG + (size_t)kc * 8192;
  #pragma unroll
  for (int p = 0; p < 8; ++p) {
    int q = 256 * p + t;          // float4 index
    load_lds16(tsrc + q * 4, &ts[q * 4]);
  }

  float accC[8], accS[8];
  #pragma unroll
  for (int r = 0; r < 8; ++r) { accC[r] = 0.f; accS[r] = 0.f; }

  __syncthreads();   // drains vmcnt(0): both tiles ready

  const float* __restrict__ xb = &xs[(w * 16 + half * 8) * 128];
  const float* __restrict__ tb = &ts[fl * 4];    // cos at +it*256, sin at +it*256+128

  #pragma unroll 8
  for (int it = 0; it < 32; ++it) {
    float4 tc = *(const float4*)(tb + it * 256);
    float4 tn = *(const float4*)(tb + it * 256 + 128);
    #pragma unroll
    for (int j = 0; j < 8; ++j) {
      float4 xv = *(const float4*)(xb + j * 128 + it * 4);
      accC[j] = fmaf(xv.w, tc.w, fmaf(xv.z, tc.z,
                fmaf(xv.y, tc.y, fmaf(xv.x, tc.x, accC[j]))));
      accS[j] = fmaf(xv.w, tn.w, fmaf(xv.z, tn.z,
                fmaf(xv.y, tn.y, fmaf(xv.x, tn.x, accS[j]))));
    }
  }

  // rows: rblock + w*16 + half*8 + j ; cols: fl (cos) and fl+32 (sin, k_fred negates)
  float* __restrict__ pp = part + ((size_t)kc * NROWS + rblock + w * 16 + half * 8) * 64;
  #pragma unroll
  for (int j = 0; j < 8; ++j) {
    pp[j * 64 + fl]      = accC[j];
    pp[j * 64 + 32 + fl] = accS[j];
  }
}

// ---------------- B2: split-K reduce -> XR_/XI_ (float4, 64 chunks) ----------------
__global__ __launch_bounds__(256) void k_fred(const float* __restrict__ part,
                                              float* __restrict__ ws) {
  int idx = blockIdx.x * 256 + threadIdx.x;   // 0..32767
  int row = idx >> 4, fq = idx & 15;
  const float4* __restrict__ p4 = (const float4*)part;
  float4 s = make_float4(0.f, 0.f, 0.f, 0.f);
  #pragma unroll 16
  for (int kc = 0; kc < 64; ++kc) {
    float4 v = p4[((size_t)kc * NROWS + row) * 16 + fq];
    s.x += v.x; s.y += v.y; s.z += v.z; s.w += v.w;
  }
  if (fq < 8) {
    *(float4*)(ws + XR_ + row * FF + fq * 4) = s;
  } else {
    float4 n = make_float4(-s.x, -s.y, -s.z, -s.w);   // rfft imag = -sum x sin
    *(float4*)(ws + XI_ + row * FF + (fq - 8) * 4) = n;
  }
}

// ---------------- B3: CFT magnitude + LayerNorm (per row) ----------------
__global__ __launch_bounds__(256) void k_cft(const float* __restrict__ x,
                                             const float* __restrict__ gamma,
                                             const float* __restrict__ beta,
                                             float* __restrict__ ws) {
  const int sub = threadIdx.x >> 6, li = threadIdx.x & 63;
  const int row = blockIdx.x * 4 + sub;
  const float* __restrict__ xr = x + (size_t)row * NN;
  __shared__ float seg[4][LM];
  #pragma unroll
  for (int g = 0; g < 3; ++g) {
    int j = li + 64 * g;
    if (j < LM) {
      int il = ((const int*)ws)[IL_ + j];
      int ir = ((const int*)ws)[IR_ + j];
      seg[sub][j] = ws[WL_ + j] * xr[il] + ws[WR_ + j] * xr[ir];
    }
  }
  __syncthreads();
  if (li < FF) {
    float re = 0.f, im = 0.f;
    #pragma unroll 8
    for (int j = 0; j < LM; ++j) {
      float sv = seg[sub][j];
      re = fmaf(sv, ws[AR_ + j * FF + li], re);
      im = fmaf(sv, ws[AI_ + j * FF + li], im);
    }
    float mag = sqrtf(re * re + im * im);
    float mu = mag;
    mu += __shfl_xor(mu, 1);  mu += __shfl_xor(mu, 2);  mu += __shfl_xor(mu, 4);
    mu += __shfl_xor(mu, 8);  mu += __shfl_xor(mu, 16);
    mu *= (1.0f / 32.0f);
    float d = mag - mu;
    float vv = d * d;
    vv += __shfl_xor(vv, 1);  vv += __shfl_xor(vv, 2);  vv += __shfl_xor(vv, 4);
    vv += __shfl_xor(vv, 8);  vv += __shfl_xor(vv, 16);
    vv *= (1.0f / 32.0f);
    float g = d / sqrtf(vv + 1e-5f) * gamma[li] + beta[li];
    ws[GN_ + row * FF + li] = g;
  }
}

// ---------------- C: gate (LN -> 1x1 conv -> sigmoid) + complex channel mix ----------------
__global__ __launch_bounds__(64) void k_gate(float* __restrict__ ws) {
  int bidx = blockIdx.x;                 // b*32 + f
  int b = bidx >> 5, f = bidx & 31;
  int o = threadIdx.x;
  __shared__ float gn[64], gr[64], gi[64];
  int rowb = b * 64;
  gn[o] = ws[GN_ + (rowb + o) * FF + f];
  float xre = ws[XR_ + (rowb + o) * FF + f];
  float xim = ws[XI_ + (rowb + o) * FF + f];
  __syncthreads();
  float acc = 0.f;
  #pragma unroll 16
  for (int i = 0; i < 64; ++i)
    acc = fmaf(ws[GWT + i * 64 + o], gn[i], acc);
  float gate = 1.0f / (1.0f + expf(-acc));
  gr[o] = xre * gate;
  gi[o] = xim * gate;
  __syncthreads();
  float Yr = 0.f, Yi = 0.f;
  const float* __restrict__ w1rt = ws + W1RT + f * 4096;
  const float* __restrict__ w1it = ws + W1IT + f * 4096;
  #pragma unroll 8
  for (int i = 0; i < 64; ++i) {
    float a = gr[i], bb2 = gi[i];
    float wr = w1rt[i * 64 + o], wi = w1it[i * 64 + o];
    Yr = fmaf(a, wr, Yr); Yr = fmaf(-bb2, wi, Yr);
    Yi = fmaf(a, wi, Yi); Yi = fmaf(bb2, wr, Yi);
  }
  float* A = ws + ARAI + (size_t)(rowb + o) * 64;
  if (f == 0) {
    A[0]  = Yr * (1.0f / (float)NN);
    A[32] = 0.0f;
  } else {
    A[f]      = Yr * (2.0f / (float)NN);
    A[32 + f] = -Yi * (2.0f / (float)NN);
  }
}

// ---------------- D: inverse (2048x64)@(64x8192) GEMM, trig streamed from L2 ----------------
__global__ __launch_bounds__(256) void k_inv(const float* __restrict__ ws,
                                             float* __restrict__ out) {
  __shared__ __align__(16) float As[32 * 64];     // 8 KB
  const int blk = blockIdx.x;
  const int bb = blk >> 5, cc = blk & 31;
  const int t = threadIdx.x;
  const int w = t >> 6, lane = t & 63;
  const int rowbase = bb * 32;
  const float* __restrict__ trigt = ws + TRIGT_;
  const int colb = cc * 256 + lane * 4;

  float4 tg0 = *(const float4*)(trigt + (size_t)0 * NN + colb);
  float4 tg1 = *(const float4*)(trigt + (size_t)1 * NN + colb);
  float4 tg2 = *(const float4*)(trigt + (size_t)2 * NN + colb);
  float4 tg3 = *(const float4*)(trigt + (size_t)3 * NN + colb);

  #pragma unroll
  for (int p = 0; p < 2; ++p) {
    int idx = t + 256 * p;
    int r = idx >> 4, q = idx & 15;
    *(float4*)(&As[r * 64 + q * 4]) =
        *(const float4*)(ws + ARAI + (size_t)(rowbase + r) * 64 + q * 4);
  }

  float4 acc[8];
  #pragma unroll
  for (int r = 0; r < 8; ++r) acc[r] = make_float4(0.f, 0.f, 0.f, 0.f);

  __syncthreads();

#define INV_STEP(F0)                                                            \
  {                                                                             \
    _Pragma("unroll")                                                           \
    for (int r = 0; r < 8; ++r) {                                               \
      float4 av = *(const float4*)(&As[(w * 8 + r) * 64 + (F0)]);               \
      acc[r].x = fmaf(av.x, tg0.x, acc[r].x); acc[r].y = fmaf(av.x, tg0.y, acc[r].y); \
      acc[r].z = fmaf(av.x, tg0.z, acc[r].z); acc[r].w = fmaf(av.x, tg0.w, acc[r].w); \
      acc[r].x = fmaf(av.y, tg1.x, acc[r].x); acc[r].y = fmaf(av.y, tg1.y, acc[r].y); \
      acc[r].z = fmaf(av.y, tg1.z, acc[r].z); acc[r].w = fmaf(av.y, tg1.w, acc[r].w); \
      acc[r].x = fmaf(av.z, tg2.x, acc[r].x); acc[r].y = fmaf(av.z, tg2.y, acc[r].y); \
      acc[r].z = fmaf(av.z, tg2.z, acc[r].z); acc[r].w = fmaf(av.z, tg2.w, acc[r].w); \
      acc[r].x = fmaf(av.w, tg3.x, acc[r].x); acc[r].y = fmaf(av.w, tg3.y, acc[r].y); \
      acc[r].z = fmaf(av.w, tg3.z, acc[r].z); acc[r].w = fmaf(av.w, tg3.w, acc[r].w); \
    }                                                                           \
  }

  for (int fo = 0; fo < 15; ++fo) {
    int f0 = fo * 4;
    float4 n0 = *(const float4*)(trigt + (size_t)(f0 + 4) * NN + colb);
    float4 n1 = *(const float4*)(trigt + (size_t)(f0 + 5) * NN + colb);
    float4 n2 = *(const float4*)(trigt + (size_t)(f0 + 6) * NN + colb);
    float4 n3 = *(const float4*)(trigt + (size_t)(f0 + 7) * NN + colb);
    INV_STEP(f0);
    tg0 = n0; tg1 = n1; tg2 = n2; tg3 = n3;
  }
  INV_STEP(60);
#undef INV_STEP

  #pragma unroll
  for (int r = 0; r < 8; ++r) {
    int row = rowbase + w * 8 + r;
    *(float4*)(out + (size_t)row * NN + colb) = acc[r];
  }
}

extern "C" void kernel_launch(void* const* d_in, const int* in_sizes, int n_in,
                              void* d_out, int out_size, void* d_ws, size_t ws_size,
                              hipStream_t stream) {
  const float* x     = (const float*)d_in[0];   // (32,64,8192)
  const float* w1r   = (const float*)d_in[1];   // (64,64,32)
  const float* w1i   = (const float*)d_in[2];   // (64,64,32)
  const float* gw    = (const float*)d_in[3];   // (64,64)
  const float* gamma = (const float*)d_in[4];   // (32,)
  const float* beta  = (const float*)d_in[5];   // (32,)
  float* out = (float*)d_out;                   // (32,64,8192)
  float* ws = (float*)d_ws;
  // split-K partials live in d_out (33.5 MB of its 64 MB) — fully overwritten by k_inv later
  float* part = (float*)d_out;

  hipLaunchKernelGGL(k_trig,       dim3(2048), dim3(256), 0, stream, ws);
  hipLaunchKernelGGL(k_cft_tables, dim3(20),   dim3(256), 0, stream, ws);
  hipLaunchKernelGGL(k_transpose,  dim3(512),  dim3(256), 0, stream, w1r, w1i, gw, ws);
  hipLaunchKernelGGL(k_fwd_gemm,   dim3(2048), dim3(256), 0, stream, x, ws, part);
  hipLaunchKernelGGL(k_fred,       dim3(128),  dim3(256), 0, stream, part, ws);
  hipLaunchKernelGGL(k_cft,        dim3(512),  dim3(256), 0, stream, x, gamma, beta, ws);
  hipLaunchKernelGGL(k_gate,       dim3(1024), dim3(64),  0, stream, ws);
  hipLaunchKernelGGL(k_inv,        dim3(2048), dim3(256), 0, stream, ws, out);
}

// Round 4
// 179.863 us; speedup vs baseline: 1.1946x; 1.1946x over previous
//
#include <hip/hip_runtime.h>
#include <hip/hip_bf16.h>
#include <math.h>

// Problem constants
// B=32, C=64 (Cin==Cout), N=8192, modes F=32, L=20 segments, M=8 Chebyshev
#define NN    8192
#define NH    4096      // N/2 — folded DFT length
#define NROWS 2048      // B*C
#define FF    32
#define LM    160       // L*M

// Workspace layout (float offsets)
// TRIG layout (folded): [k4][f][4], k4=0..1023 (j=4*k4+e, j<4096):
//   ws[TRIG + (k4*64+f)*4 + e] = f<32 ? cos(2pi f (4k4+e)/N) : sin(2pi (f-32)(4k4+e)/N)
// TRIGT layout (folded): [f][j] j<4096 (rows 0..31 cos, 32..63 sin) — for k_inv
static constexpr int TRIG   = 0;         // 1024*64*4 = 262144 floats used
static constexpr int W1RT   = 524288;    // [f][i][o] 32*64*64
static constexpr int W1IT   = 655360;
static constexpr int GWT    = 786432;    // [i][o] 64*64
static constexpr int AR_    = 790528;    // [160][32]
static constexpr int AI_    = 795648;
static constexpr int WL_    = 800768;    // [160]
static constexpr int WR_    = 800928;
static constexpr int IL_    = 801088;    // int [160]
static constexpr int IR_    = 801248;
static constexpr int XR_    = 801408;    // [2048][32]
static constexpr int XI_    = 866944;
static constexpr int GN_    = 932480;    // [2048][32]
static constexpr int ARAI   = 998016;    // [2048][64]: [0..31]=cos coeff, [32..63]=sin coeff
static constexpr int TRIGT_ = 1129088;   // [64][4096] = 262144 floats used

#define PI_D 3.14159265358979323846

// async global->LDS, 16 bytes per lane (dest must be linear in lane: base + lane*16)
__device__ __forceinline__ void load_lds16(const float* g, float* l) {
  __builtin_amdgcn_global_load_lds(
      (const __attribute__((address_space(1))) void*)g,
      (__attribute__((address_space(3))) void*)l, 16, 0, 0);
}

// ---------------- A1: trig tables (both layouts, folded to j<4096) ----------------
__global__ __launch_bounds__(256) void k_trig(float* __restrict__ ws) {
  int idx = blockIdx.x * 256 + threadIdx.x;   // 0..262143
  int k4 = idx >> 8, f = (idx >> 2) & 63, e = idx & 3;
  int n = 4 * k4 + e;                          // 0..4095
  int fr = f & 31;
  int p = (fr * n) & (NN - 1);
  float ang = (float)p * (float)(2.0 * PI_D / (double)NN);
  float s, c;
  sincosf(ang, &s, &c);
  float v = (f < 32) ? c : s;
  ws[TRIG + idx] = v;
  ws[TRIGT_ + f * NH + n] = v;
}

// ---------------- A2: CFT constant tables (double precision, parallel) ----------------
__global__ __launch_bounds__(256) void k_cft_tables(float* __restrict__ ws) {
  int tid = blockIdx.x * 256 + threadIdx.x;
  if (tid >= LM * FF) return;
  int j = tid >> 5, f = tid & 31;
  int l = j >> 3, m = j & 7;      // m doubles as Chebyshev order k
  const double cheb[8] = {
    -0.98078528040323044913, -0.83146961230254523708,
    -0.55557023301960222474, -0.19509032201612826785,
     0.19509032201612826785,  0.55557023301960222474,
     0.83146961230254523708,  0.98078528040323044913 };

  double Wr = 0.0, Wi = 0.0;
  #pragma unroll
  for (int mm = 0; mm < 8; ++mm) {
    double c = cheb[mm];
    double T;
    if (m == 0) T = 1.0;
    else {
      double a = 1.0, b = c;
      for (int q = 1; q < m; ++q) { double t = 2.0 * c * b - a; a = b; b = t; }
      T = b;
    }
    double ang = c * (double)f * (PI_D * 0.05);
    Wr += T * cos(ang);
    Wi += T * (-sin(ang));
  }
  Wr *= 0.025; Wi *= 0.025;
  double phi = 2.0 * PI_D * ((double)l * 0.05) * (double)f;
  double cs = cos(phi), sn = sin(phi);
  ws[AR_ + j * FF + f] = (float)(Wr * cs + Wi * sn);
  ws[AI_ + j * FF + f] = (float)(-Wr * sn + Wi * cs);

  if (f == 0) {
    double v = (double)l * 0.05 + 0.025 * (cheb[m] + 1.0);
    int r = (int)(v * 8191.0);
    while ((double)r / 8191.0 < v) ++r;
    while (r > 0 && (double)(r - 1) / 8191.0 >= v) --r;
    if (r > 8191) r = 8191;
    int le = r - 1; if (le < 0) le = 0;
    double tl = (double)le / 8191.0, tr = (double)r / 8191.0;
    double den = (tr - tl == 0.0) ? 1.0 : (tr - tl);
    double wr = (v - tl) / den;
    ws[WL_ + j] = (float)(1.0 - wr);
    ws[WR_ + j] = (float)wr;
    ((int*)ws)[IL_ + j] = le;
    ((int*)ws)[IR_ + j] = r;
  }
}

// ---------------- A3: transposes ----------------
__global__ __launch_bounds__(256) void k_transpose(const float* __restrict__ w1r,
                                                   const float* __restrict__ w1i,
                                                   const float* __restrict__ gw,
                                                   float* __restrict__ ws) {
  int idx = blockIdx.x * 256 + threadIdx.x;   // 0..131071
  if (idx >= 32 * 64 * 64) return;
  int o = idx & 63, i = (idx >> 6) & 63, f = idx >> 12;   // f in 0..31
  ws[W1RT + (f * 64 + i) * 64 + o] = w1r[(i * 64 + o) * FF + f];
  ws[W1IT + (f * 64 + i) * 64 + o] = w1i[(i * 64 + o) * FF + f];
  if (idx < 4096) {
    ws[GWT + idx] = gw[(idx & 63) * 64 + (idx >> 6)];
  }
}

// ---------------- B1: folded forward DFT, split-K GEMM ----------------
// X[f] = sum_{j<4096} s_f[j] (cos - i sin), s_f = u (f even) / w (f odd),
// u[j]=x[j]+x[j+4096], w[j]=x[j]-x[j+4096]  — FLOPs halved vs full DFT.
// grid = 32 row-tiles (64 rows) x 64 j-chunks (64 j). ONE barrier.
// Staging: u/w computed in registers -> bank-skewed LDS (u | 16-float pad | w,
// so the 4 broadcast lines per ds_read_b128 land in 2 bank groups).
// Trig chunk (16 KB) DMA'd via global_load_lds. LDS total 48.8 KB -> 3 blocks/CU.
// Inner loop: pure immediate-offset ds_read_b128 + FMA, zero address VALU.
__global__ __launch_bounds__(256) void k_fwd_gemm(const float* __restrict__ x,
                                                  const float* __restrict__ ws,
                                                  float* __restrict__ part) {
  __shared__ __align__(16) float uw[4096 + 16 + 4096];  // u | pad | w (32.8 KB)
  __shared__ __align__(16) float ts[16 * 256];          // 16 KB trig [it][fslot][4]
  const int rt = blockIdx.x >> 6, jc = blockIdx.x & 63;
  const int t = threadIdx.x;
  const int w = t >> 6, lane = t & 63;
  const int half = lane >> 5, fl = lane & 31;
  const int rblock = rt * 64;
  const int jb = jc * 64;

  // trig chunk DMA: contiguous 16 KB at TRIG + jc*16*256
  const float* __restrict__ tsrc = ws + TRIG + (size_t)jc * 4096;
  #pragma unroll
  for (int p = 0; p < 4; ++p) {
    int q = 256 * p + t;                 // float4 index, linear in t
    load_lds16(tsrc + q * 4, &ts[q * 4]);
  }

  // u/w staging: 64 rows x 64 j = 1024 float4 per array, 4 per thread
  #pragma unroll
  for (int p = 0; p < 4; ++p) {
    int idx = 256 * p + t;
    int row = idx >> 4, c4 = idx & 15;
    const float* __restrict__ xp = x + (size_t)(rblock + row) * NN + jb + c4 * 4;
    float4 a = *(const float4*)xp;
    float4 b = *(const float4*)(xp + NH);
    float4 u = make_float4(a.x + b.x, a.y + b.y, a.z + b.z, a.w + b.w);
    float4 v = make_float4(a.x - b.x, a.y - b.y, a.z - b.z, a.w - b.w);
    *(float4*)(&uw[row * 64 + c4 * 4]) = u;
    *(float4*)(&uw[4112 + row * 64 + c4 * 4]) = v;
  }

  float accC[8], accS[8];
  #pragma unroll
  for (int r = 0; r < 8; ++r) { accC[r] = 0.f; accS[r] = 0.f; }

  __syncthreads();   // drains vmcnt(0) + lgkmcnt(0): trig DMA + u/w writes done

  // per-lane fixed bases: parity picks u or w; rows w*16 + half*8 + j
  const float* __restrict__ xb = &uw[(fl & 1) * 4112 + (w * 16 + half * 8) * 64];
  const float* __restrict__ tb = &ts[fl * 4];    // cos at +it*256, sin at +128

  #pragma unroll
  for (int it = 0; it < 16; ++it) {
    float4 tc = *(const float4*)(tb + it * 256);
    float4 tn = *(const float4*)(tb + it * 256 + 128);
    #pragma unroll
    for (int j = 0; j < 8; ++j) {
      float4 xv = *(const float4*)(xb + j * 64 + it * 4);
      accC[j] = fmaf(xv.w, tc.w, fmaf(xv.z, tc.z,
                fmaf(xv.y, tc.y, fmaf(xv.x, tc.x, accC[j]))));
      accS[j] = fmaf(xv.w, tn.w, fmaf(xv.z, tn.z,
                fmaf(xv.y, tn.y, fmaf(xv.x, tn.x, accS[j]))));
    }
  }

  // rows: rblock + w*16 + half*8 + j ; cols: fl (cos) and fl+32 (sin, k_fred negates)
  float* __restrict__ pp = part + ((size_t)jc * NROWS + rblock + w * 16 + half * 8) * 64;
  #pragma unroll
  for (int j = 0; j < 8; ++j) {
    pp[j * 64 + fl]      = accC[j];
    pp[j * 64 + 32 + fl] = accS[j];
  }
}

// ---------------- B2: split-K reduce -> XR_/XI_ (float4, 64 chunks) ----------------
__global__ __launch_bounds__(256) void k_fred(const float* __restrict__ part,
                                              float* __restrict__ ws) {
  int idx = blockIdx.x * 256 + threadIdx.x;   // 0..32767
  int row = idx >> 4, fq = idx & 15;
  const float4* __restrict__ p4 = (const float4*)part;
  float4 s = make_float4(0.f, 0.f, 0.f, 0.f);
  #pragma unroll 16
  for (int kc = 0; kc < 64; ++kc) {
    float4 v = p4[((size_t)kc * NROWS + row) * 16 + fq];
    s.x += v.x; s.y += v.y; s.z += v.z; s.w += v.w;
  }
  if (fq < 8) {
    *(float4*)(ws + XR_ + row * FF + fq * 4) = s;
  } else {
    float4 n = make_float4(-s.x, -s.y, -s.z, -s.w);   // rfft imag = -sum x sin
    *(float4*)(ws + XI_ + row * FF + (fq - 8) * 4) = n;
  }
}

// ---------------- B3: CFT magnitude + LayerNorm (per row) ----------------
__global__ __launch_bounds__(256) void k_cft(const float* __restrict__ x,
                                             const float* __restrict__ gamma,
                                             const float* __restrict__ beta,
                                             float* __restrict__ ws) {
  const int sub = threadIdx.x >> 6, li = threadIdx.x & 63;
  const int row = blockIdx.x * 4 + sub;
  const float* __restrict__ xr = x + (size_t)row * NN;
  __shared__ float seg[4][LM];
  #pragma unroll
  for (int g = 0; g < 3; ++g) {
    int j = li + 64 * g;
    if (j < LM) {
      int il = ((const int*)ws)[IL_ + j];
      int ir = ((const int*)ws)[IR_ + j];
      seg[sub][j] = ws[WL_ + j] * xr[il] + ws[WR_ + j] * xr[ir];
    }
  }
  __syncthreads();
  if (li < FF) {
    float re = 0.f, im = 0.f;
    #pragma unroll 8
    for (int j = 0; j < LM; ++j) {
      float sv = seg[sub][j];
      re = fmaf(sv, ws[AR_ + j * FF + li], re);
      im = fmaf(sv, ws[AI_ + j * FF + li], im);
    }
    float mag = sqrtf(re * re + im * im);
    float mu = mag;
    mu += __shfl_xor(mu, 1);  mu += __shfl_xor(mu, 2);  mu += __shfl_xor(mu, 4);
    mu += __shfl_xor(mu, 8);  mu += __shfl_xor(mu, 16);
    mu *= (1.0f / 32.0f);
    float d = mag - mu;
    float vv = d * d;
    vv += __shfl_xor(vv, 1);  vv += __shfl_xor(vv, 2);  vv += __shfl_xor(vv, 4);
    vv += __shfl_xor(vv, 8);  vv += __shfl_xor(vv, 16);
    vv *= (1.0f / 32.0f);
    float g = d / sqrtf(vv + 1e-5f) * gamma[li] + beta[li];
    ws[GN_ + row * FF + li] = g;
  }
}

// ---------------- C: gate (LN -> 1x1 conv -> sigmoid) + complex channel mix ----------------
__global__ __launch_bounds__(64) void k_gate(float* __restrict__ ws) {
  int bidx = blockIdx.x;                 // b*32 + f
  int b = bidx >> 5, f = bidx & 31;
  int o = threadIdx.x;
  __shared__ float gn[64], gr[64], gi[64];
  int rowb = b * 64;
  gn[o] = ws[GN_ + (rowb + o) * FF + f];
  float xre = ws[XR_ + (rowb + o) * FF + f];
  float xim = ws[XI_ + (rowb + o) * FF + f];
  __syncthreads();
  float acc = 0.f;
  #pragma unroll 16
  for (int i = 0; i < 64; ++i)
    acc = fmaf(ws[GWT + i * 64 + o], gn[i], acc);
  float gate = 1.0f / (1.0f + expf(-acc));
  gr[o] = xre * gate;
  gi[o] = xim * gate;
  __syncthreads();
  float Yr = 0.f, Yi = 0.f;
  const float* __restrict__ w1rt = ws + W1RT + f * 4096;
  const float* __restrict__ w1it = ws + W1IT + f * 4096;
  #pragma unroll 8
  for (int i = 0; i < 64; ++i) {
    float a = gr[i], bb2 = gi[i];
    float wr = w1rt[i * 64 + o], wi = w1it[i * 64 + o];
    Yr = fmaf(a, wr, Yr); Yr = fmaf(-bb2, wi, Yr);
    Yi = fmaf(a, wi, Yi); Yi = fmaf(bb2, wr, Yi);
  }
  float* A = ws + ARAI + (size_t)(rowb + o) * 64;
  if (f == 0) {
    A[0]  = Yr * (1.0f / (float)NN);
    A[32] = 0.0f;
  } else {
    A[f]      = Yr * (2.0f / (float)NN);
    A[32 + f] = -Yi * (2.0f / (float)NN);
  }
}

// ---------------- D: folded inverse (2048x64)@(64x4096) -> mirrored pair ----------------
// out[j]      = E[j] + O[j],  out[j+4096] = E[j] - O[j],
// E = sum over even f of (Ar cos + Ai sin), O = same over odd f.
// grid = 64 row-groups(32 rows) x 16 col-chunks(256 j) = 1024 blocks (halved FLOPs).
__global__ __launch_bounds__(256) void k_inv(const float* __restrict__ ws,
                                             float* __restrict__ out) {
  __shared__ __align__(16) float As[32 * 64];     // 8 KB
  const int blk = blockIdx.x;
  const int bb = blk >> 4, cc = blk & 15;
  const int t = threadIdx.x;
  const int w = t >> 6, lane = t & 63;
  const int rowbase = bb * 32;
  const float* __restrict__ trigt = ws + TRIGT_;
  const int colb = cc * 256 + lane * 4;           // 0..4092

  float4 tg0 = *(const float4*)(trigt + (size_t)0 * NH + colb);
  float4 tg1 = *(const float4*)(trigt + (size_t)1 * NH + colb);
  float4 tg2 = *(const float4*)(trigt + (size_t)2 * NH + colb);
  float4 tg3 = *(const float4*)(trigt + (size_t)3 * NH + colb);

  #pragma unroll
  for (int p = 0; p < 2; ++p) {
    int idx = t + 256 * p;
    int r = idx >> 4, q = idx & 15;
    *(float4*)(&As[r * 64 + q * 4]) =
        *(const float4*)(ws + ARAI + (size_t)(rowbase + r) * 64 + q * 4);
  }

  float4 accE[8], accO[8];
  #pragma unroll
  for (int r = 0; r < 8; ++r) {
    accE[r] = make_float4(0.f, 0.f, 0.f, 0.f);
    accO[r] = make_float4(0.f, 0.f, 0.f, 0.f);
  }

  __syncthreads();

// f-slots F0..F0+3 have frequency parity even,odd,even,odd (F0 % 4 == 0):
// components .x/.z accumulate into E, .y/.w into O.
#define INV_STEP(F0)                                                            \
  {                                                                             \
    _Pragma("unroll")                                                           \
    for (int r = 0; r < 8; ++r) {                                               \
      float4 av = *(const float4*)(&As[(w * 8 + r) * 64 + (F0)]);               \
      accE[r].x = fmaf(av.x, tg0.x, accE[r].x); accE[r].y = fmaf(av.x, tg0.y, accE[r].y); \
      accE[r].z = fmaf(av.x, tg0.z, accE[r].z); accE[r].w = fmaf(av.x, tg0.w, accE[r].w); \
      accO[r].x = fmaf(av.y, tg1.x, accO[r].x); accO[r].y = fmaf(av.y, tg1.y, accO[r].y); \
      accO[r].z = fmaf(av.y, tg1.z, accO[r].z); accO[r].w = fmaf(av.y, tg1.w, accO[r].w); \
      accE[r].x = fmaf(av.z, tg2.x, accE[r].x); accE[r].y = fmaf(av.z, tg2.y, accE[r].y); \
      accE[r].z = fmaf(av.z, tg2.z, accE[r].z); accE[r].w = fmaf(av.z, tg2.w, accE[r].w); \
      accO[r].x = fmaf(av.w, tg3.x, accO[r].x); accO[r].y = fmaf(av.w, tg3.y, accO[r].y); \
      accO[r].z = fmaf(av.w, tg3.z, accO[r].z); accO[r].w = fmaf(av.w, tg3.w, accO[r].w); \
    }                                                                           \
  }

  for (int fo = 0; fo < 15; ++fo) {
    int f0 = fo * 4;
    float4 n0 = *(const float4*)(trigt + (size_t)(f0 + 4) * NH + colb);
    float4 n1 = *(const float4*)(trigt + (size_t)(f0 + 5) * NH + colb);
    float4 n2 = *(const float4*)(trigt + (size_t)(f0 + 6) * NH + colb);
    float4 n3 = *(const float4*)(trigt + (size_t)(f0 + 7) * NH + colb);
    INV_STEP(f0);
    tg0 = n0; tg1 = n1; tg2 = n2; tg3 = n3;
  }
  INV_STEP(60);
#undef INV_STEP

  #pragma unroll
  for (int r = 0; r < 8; ++r) {
    int row = rowbase + w * 8 + r;
    float4 E = accE[r], O = accO[r];
    float4 s0 = make_float4(E.x + O.x, E.y + O.y, E.z + O.z, E.w + O.w);
    float4 s1 = make_float4(E.x - O.x, E.y - O.y, E.z - O.z, E.w - O.w);
    *(float4*)(out + (size_t)row * NN + colb)      = s0;
    *(float4*)(out + (size_t)row * NN + colb + NH) = s1;
  }
}

extern "C" void kernel_launch(void* const* d_in, const int* in_sizes, int n_in,
                              void* d_out, int out_size, void* d_ws, size_t ws_size,
                              hipStream_t stream) {
  const float* x     = (const float*)d_in[0];   // (32,64,8192)
  const float* w1r   = (const float*)d_in[1];   // (64,64,32)
  const float* w1i   = (const float*)d_in[2];   // (64,64,32)
  const float* gw    = (const float*)d_in[3];   // (64,64)
  const float* gamma = (const float*)d_in[4];   // (32,)
  const float* beta  = (const float*)d_in[5];   // (32,)
  float* out = (float*)d_out;                   // (32,64,8192)
  float* ws = (float*)d_ws;
  // split-K partials live in d_out (33.5 MB of its 64 MB) — fully overwritten by k_inv later
  float* part = (float*)d_out;

  hipLaunchKernelGGL(k_trig,       dim3(1024), dim3(256), 0, stream, ws);
  hipLaunchKernelGGL(k_cft_tables, dim3(20),   dim3(256), 0, stream, ws);
  hipLaunchKernelGGL(k_transpose,  dim3(512),  dim3(256), 0, stream, w1r, w1i, gw, ws);
  hipLaunchKernelGGL(k_fwd_gemm,   dim3(2048), dim3(256), 0, stream, x, ws, part);
  hipLaunchKernelGGL(k_fred,       dim3(128),  dim3(256), 0, stream, part, ws);
  hipLaunchKernelGGL(k_cft,        dim3(512),  dim3(256), 0, stream, x, gamma, beta, ws);
  hipLaunchKernelGGL(k_gate,       dim3(1024), dim3(64),  0, stream, ws);
  hipLaunchKernelGGL(k_inv,        dim3(1024), dim3(256), 0, stream, ws, out);
}

// Round 5
// 178.299 us; speedup vs baseline: 1.2051x; 1.0088x over previous
//
#include <hip/hip_runtime.h>
#include <hip/hip_bf16.h>
#include <math.h>

// Problem constants
// B=32, C=64 (Cin==Cout), N=8192, modes F=32, L=20 segments, M=8 Chebyshev
#define NN    8192
#define NH    4096      // N/2 — folded DFT length
#define NROWS 2048      // B*C
#define FF    32
#define LM    160       // L*M

// Workspace layout (float offsets)
// TRIG layout (folded): [k4][f][4], k4=0..1023 (j=4*k4+e, j<4096):
//   ws[TRIG + (k4*64+f)*4 + e] = f<32 ? cos(2pi f (4k4+e)/N) : sin(2pi (f-32)(4k4+e)/N)
// TRIGT layout (folded): [f][j] j<4096 (rows 0..31 cos, 32..63 sin) — for k_inv
static constexpr int TRIG   = 0;         // 1024*64*4 = 262144 floats used
static constexpr int W1RT   = 524288;    // [f][i][o] 32*64*64
static constexpr int W1IT   = 655360;
static constexpr int GWT    = 786432;    // [i][o] 64*64
static constexpr int AR_    = 790528;    // [160][32]
static constexpr int AI_    = 795648;
static constexpr int WL_    = 800768;    // [160]
static constexpr int WR_    = 800928;
static constexpr int IL_    = 801088;    // int [160]
static constexpr int IR_    = 801248;
static constexpr int XR_    = 801408;    // [2048][32]
static constexpr int XI_    = 866944;
static constexpr int GN_    = 932480;    // [2048][32]
static constexpr int ARAI   = 998016;    // [2048][64]: [0..31]=cos coeff, [32..63]=sin coeff
static constexpr int TRIGT_ = 1129088;   // [64][4096] = 262144 floats used

#define PI_D 3.14159265358979323846

// ---------------- K1: all setup (trig tables | CFT tables | transposes) ----------------
// blocks [0,1024)      : trig tables (folded, both layouts)
// blocks [1024,1044)   : CFT constant tables
// blocks [1044,1556)   : w1 / gate_w transposes
__global__ __launch_bounds__(256) void k_setup(const float* __restrict__ w1r,
                                               const float* __restrict__ w1i,
                                               const float* __restrict__ gw,
                                               float* __restrict__ ws) {
  const int bid = blockIdx.x, tid = threadIdx.x;

  if (bid < 1024) {
    // ---- trig ----
    int idx = bid * 256 + tid;                  // 0..262143
    int k4 = idx >> 8, f = (idx >> 2) & 63, e = idx & 3;
    int n = 4 * k4 + e;                          // 0..4095
    int fr = f & 31;
    int p = (fr * n) & (NN - 1);
    float ang = (float)p * (float)(2.0 * PI_D / (double)NN);
    float s, c;
    sincosf(ang, &s, &c);
    float v = (f < 32) ? c : s;
    ws[TRIG + idx] = v;
    ws[TRIGT_ + f * NH + n] = v;
    return;
  }

  if (bid < 1044) {
    // ---- CFT tables ----
    int t2 = (bid - 1024) * 256 + tid;
    if (t2 >= LM * FF) return;
    int j = t2 >> 5, f = t2 & 31;
    int l = j >> 3, m = j & 7;
    const double cheb[8] = {
      -0.98078528040323044913, -0.83146961230254523708,
      -0.55557023301960222474, -0.19509032201612826785,
       0.19509032201612826785,  0.55557023301960222474,
       0.83146961230254523708,  0.98078528040323044913 };

    double Wr = 0.0, Wi = 0.0;
    #pragma unroll
    for (int mm = 0; mm < 8; ++mm) {
      double c = cheb[mm];
      double T;
      if (m == 0) T = 1.0;
      else {
        double a = 1.0, b = c;
        for (int q = 1; q < m; ++q) { double t = 2.0 * c * b - a; a = b; b = t; }
        T = b;
      }
      double ang = c * (double)f * (PI_D * 0.05);
      Wr += T * cos(ang);
      Wi += T * (-sin(ang));
    }
    Wr *= 0.025; Wi *= 0.025;
    double phi = 2.0 * PI_D * ((double)l * 0.05) * (double)f;
    double cs = cos(phi), sn = sin(phi);
    ws[AR_ + j * FF + f] = (float)(Wr * cs + Wi * sn);
    ws[AI_ + j * FF + f] = (float)(-Wr * sn + Wi * cs);

    if (f == 0) {
      double v = (double)l * 0.05 + 0.025 * (cheb[m] + 1.0);
      int r = (int)(v * 8191.0);
      while ((double)r / 8191.0 < v) ++r;
      while (r > 0 && (double)(r - 1) / 8191.0 >= v) --r;
      if (r > 8191) r = 8191;
      int le = r - 1; if (le < 0) le = 0;
      double tl = (double)le / 8191.0, tr = (double)r / 8191.0;
      double den = (tr - tl == 0.0) ? 1.0 : (tr - tl);
      double wr = (v - tl) / den;
      ws[WL_ + j] = (float)(1.0 - wr);
      ws[WR_ + j] = (float)wr;
      ((int*)ws)[IL_ + j] = le;
      ((int*)ws)[IR_ + j] = r;
    }
    return;
  }

  // ---- transposes ----
  {
    int idx = (bid - 1044) * 256 + tid;         // 0..131071
    if (idx >= 32 * 64 * 64) return;
    int o = idx & 63, i = (idx >> 6) & 63, f = idx >> 12;
    ws[W1RT + (f * 64 + i) * 64 + o] = w1r[(i * 64 + o) * FF + f];
    ws[W1IT + (f * 64 + i) * 64 + o] = w1i[(i * 64 + o) * FF + f];
    if (idx < 4096) {
      ws[GWT + idx] = gw[(idx & 63) * 64 + (idx >> 6)];
    }
  }
}

// ---------------- K2: folded forward DFT (split-K) + CFT/LayerNorm ----------------
// blocks [0,2048): forward folded DFT. X[f] = sum_{j<4096} s_f[j](cos - i sin),
//   s_f = u (f even) / w (f odd), u=x[j]+x[j+4096], w=x[j]-x[j+4096].
//   grid 32 row-tiles (64 rows) x 64 j-chunks (64 j). ONE barrier.
//   u/w in bank-skewed LDS (33 KB -> 4 blocks/CU); trig streamed from L2 in
//   registers (2-way broadcast, one-ahead prefetch) — round-0-proven pattern,
//   no vmcnt drain at the barrier.
// blocks [2048,2560): CFT magnitude + LayerNorm (independent of the DFT; hides
//   its scattered x gather under the GEMM).
__global__ __launch_bounds__(256) void k_fwd(const float* __restrict__ x,
                                             float* __restrict__ ws,
                                             float* __restrict__ part,
                                             const float* __restrict__ gamma,
                                             const float* __restrict__ beta) {
  __shared__ __align__(16) float smem[4096 + 16 + 4096];  // fwd: u|pad|w; cft: seg[4][LM]
  const int bid = blockIdx.x;
  const int t = threadIdx.x;

  if (bid < 2048) {
    const int rt = bid >> 6, jc = bid & 63;
    const int w = t >> 6, lane = t & 63;
    const int half = lane >> 5, fl = lane & 31;
    const int rblock = rt * 64;
    const int jb = jc * 64;

    // u/w staging: 64 rows x 64 j = 1024 float4 per array, 4 per thread
    #pragma unroll
    for (int p = 0; p < 4; ++p) {
      int idx = 256 * p + t;
      int row = idx >> 4, c4 = idx & 15;
      const float* __restrict__ xp = x + (size_t)(rblock + row) * NN + jb + c4 * 4;
      float4 a = *(const float4*)xp;
      float4 b = *(const float4*)(xp + NH);
      float4 u = make_float4(a.x + b.x, a.y + b.y, a.z + b.z, a.w + b.w);
      float4 v = make_float4(a.x - b.x, a.y - b.y, a.z - b.z, a.w - b.w);
      *(float4*)(&smem[row * 64 + c4 * 4]) = u;
      *(float4*)(&smem[4112 + row * 64 + c4 * 4]) = v;
    }

    float accC[8], accS[8];
    #pragma unroll
    for (int r = 0; r < 8; ++r) { accC[r] = 0.f; accS[r] = 0.f; }

    __syncthreads();

    // per-lane fixed base: parity picks u or w; rows w*16 + half*8 ..+7
    const float* __restrict__ xb = &smem[(fl & 1) * 4112 + (w * 16 + half * 8) * 64];
    const float4* __restrict__ tg4 = (const float4*)(ws + TRIG);
    const size_t gb = (size_t)(jc * 16) * 64;

#define FWD_STEP(IT, TC, TS)                                                    \
    {                                                                           \
      _Pragma("unroll")                                                         \
      for (int j = 0; j < 8; ++j) {                                             \
        float4 xv = *(const float4*)(xb + j * 64 + (IT) * 4);                   \
        accC[j] = fmaf(xv.w, (TC).w, fmaf(xv.z, (TC).z,                         \
                  fmaf(xv.y, (TC).y, fmaf(xv.x, (TC).x, accC[j]))));            \
        accS[j] = fmaf(xv.w, (TS).w, fmaf(xv.z, (TS).z,                         \
                  fmaf(xv.y, (TS).y, fmaf(xv.x, (TS).x, accS[j]))));            \
      }                                                                         \
    }

    float4 tc = tg4[gb + fl];
    float4 tn = tg4[gb + 32 + fl];
    #pragma unroll 5
    for (int it = 0; it < 15; ++it) {
      float4 tc2 = tg4[gb + (size_t)(it + 1) * 64 + fl];      // prefetch next
      float4 tn2 = tg4[gb + (size_t)(it + 1) * 64 + 32 + fl];
      FWD_STEP(it, tc, tn);
      tc = tc2; tn = tn2;
    }
    FWD_STEP(15, tc, tn);
#undef FWD_STEP

    // rows: rblock + w*16 + half*8 + j ; cols: fl (cos), fl+32 (sin, k_fred negates)
    float* __restrict__ pp = part + ((size_t)jc * NROWS + rblock + w * 16 + half * 8) * 64;
    #pragma unroll
    for (int j = 0; j < 8; ++j) {
      pp[j * 64 + fl]      = accC[j];
      pp[j * 64 + 32 + fl] = accS[j];
    }
    return;
  }

  // ---- CFT magnitude + LayerNorm ----
  {
    const int cb = bid - 2048;
    const int sub = t >> 6, li = t & 63;
    const int row = cb * 4 + sub;
    const float* __restrict__ xr = x + (size_t)row * NN;
    float (*seg)[LM] = (float (*)[LM])smem;
    #pragma unroll
    for (int g = 0; g < 3; ++g) {
      int j = li + 64 * g;
      if (j < LM) {
        int il = ((const int*)ws)[IL_ + j];
        int ir = ((const int*)ws)[IR_ + j];
        seg[sub][j] = ws[WL_ + j] * xr[il] + ws[WR_ + j] * xr[ir];
      }
    }
    __syncthreads();
    if (li < FF) {
      float re = 0.f, im = 0.f;
      #pragma unroll 8
      for (int j = 0; j < LM; ++j) {
        float sv = seg[sub][j];
        re = fmaf(sv, ws[AR_ + j * FF + li], re);
        im = fmaf(sv, ws[AI_ + j * FF + li], im);
      }
      float mag = sqrtf(re * re + im * im);
      float mu = mag;
      mu += __shfl_xor(mu, 1);  mu += __shfl_xor(mu, 2);  mu += __shfl_xor(mu, 4);
      mu += __shfl_xor(mu, 8);  mu += __shfl_xor(mu, 16);
      mu *= (1.0f / 32.0f);
      float d = mag - mu;
      float vv = d * d;
      vv += __shfl_xor(vv, 1);  vv += __shfl_xor(vv, 2);  vv += __shfl_xor(vv, 4);
      vv += __shfl_xor(vv, 8);  vv += __shfl_xor(vv, 16);
      vv *= (1.0f / 32.0f);
      float g = d / sqrtf(vv + 1e-5f) * gamma[li] + beta[li];
      ws[GN_ + row * FF + li] = g;
    }
  }
}

// ---------------- K3: split-K reduce -> XR_/XI_ (float4, 64 chunks) ----------------
__global__ __launch_bounds__(256) void k_fred(const float* __restrict__ part,
                                              float* __restrict__ ws) {
  int idx = blockIdx.x * 256 + threadIdx.x;   // 0..32767
  int row = idx >> 4, fq = idx & 15;
  const float4* __restrict__ p4 = (const float4*)part;
  float4 s = make_float4(0.f, 0.f, 0.f, 0.f);
  #pragma unroll 16
  for (int kc = 0; kc < 64; ++kc) {
    float4 v = p4[((size_t)kc * NROWS + row) * 16 + fq];
    s.x += v.x; s.y += v.y; s.z += v.z; s.w += v.w;
  }
  if (fq < 8) {
    *(float4*)(ws + XR_ + row * FF + fq * 4) = s;
  } else {
    float4 n = make_float4(-s.x, -s.y, -s.z, -s.w);   // rfft imag = -sum x sin
    *(float4*)(ws + XI_ + row * FF + (fq - 8) * 4) = n;
  }
}

// ---------------- K4: gate (LN -> 1x1 conv -> sigmoid) + complex channel mix ----------------
__global__ __launch_bounds__(64) void k_gate(float* __restrict__ ws) {
  int bidx = blockIdx.x;                 // b*32 + f
  int b = bidx >> 5, f = bidx & 31;
  int o = threadIdx.x;
  __shared__ float gn[64], gr[64], gi[64];
  int rowb = b * 64;
  gn[o] = ws[GN_ + (rowb + o) * FF + f];
  float xre = ws[XR_ + (rowb + o) * FF + f];
  float xim = ws[XI_ + (rowb + o) * FF + f];
  __syncthreads();
  float acc = 0.f;
  #pragma unroll 16
  for (int i = 0; i < 64; ++i)
    acc = fmaf(ws[GWT + i * 64 + o], gn[i], acc);
  float gate = 1.0f / (1.0f + expf(-acc));
  gr[o] = xre * gate;
  gi[o] = xim * gate;
  __syncthreads();
  float Yr = 0.f, Yi = 0.f;
  const float* __restrict__ w1rt = ws + W1RT + f * 4096;
  const float* __restrict__ w1it = ws + W1IT + f * 4096;
  #pragma unroll 8
  for (int i = 0; i < 64; ++i) {
    float a = gr[i], bb2 = gi[i];
    float wr = w1rt[i * 64 + o], wi = w1it[i * 64 + o];
    Yr = fmaf(a, wr, Yr); Yr = fmaf(-bb2, wi, Yr);
    Yi = fmaf(a, wi, Yi); Yi = fmaf(bb2, wr, Yi);
  }
  float* A = ws + ARAI + (size_t)(rowb + o) * 64;
  if (f == 0) {
    A[0]  = Yr * (1.0f / (float)NN);
    A[32] = 0.0f;
  } else {
    A[f]      = Yr * (2.0f / (float)NN);
    A[32 + f] = -Yi * (2.0f / (float)NN);
  }
}

// ---------------- K5: folded inverse (2048x64)@(64x4096) -> mirrored pair ----------------
// out[j] = E[j]+O[j], out[j+4096] = E[j]-O[j]; E/O = even/odd-f partial sums.
__global__ __launch_bounds__(256) void k_inv(const float* __restrict__ ws,
                                             float* __restrict__ out) {
  __shared__ __align__(16) float As[32 * 64];     // 8 KB
  const int blk = blockIdx.x;
  const int bb = blk >> 4, cc = blk & 15;
  const int t = threadIdx.x;
  const int w = t >> 6, lane = t & 63;
  const int rowbase = bb * 32;
  const float* __restrict__ trigt = ws + TRIGT_;
  const int colb = cc * 256 + lane * 4;           // 0..4092

  float4 tg0 = *(const float4*)(trigt + (size_t)0 * NH + colb);
  float4 tg1 = *(const float4*)(trigt + (size_t)1 * NH + colb);
  float4 tg2 = *(const float4*)(trigt + (size_t)2 * NH + colb);
  float4 tg3 = *(const float4*)(trigt + (size_t)3 * NH + colb);

  #pragma unroll
  for (int p = 0; p < 2; ++p) {
    int idx = t + 256 * p;
    int r = idx >> 4, q = idx & 15;
    *(float4*)(&As[r * 64 + q * 4]) =
        *(const float4*)(ws + ARAI + (size_t)(rowbase + r) * 64 + q * 4);
  }

  float4 accE[8], accO[8];
  #pragma unroll
  for (int r = 0; r < 8; ++r) {
    accE[r] = make_float4(0.f, 0.f, 0.f, 0.f);
    accO[r] = make_float4(0.f, 0.f, 0.f, 0.f);
  }

  __syncthreads();

// f-slots F0..F0+3 have parity even,odd,even,odd (F0 % 4 == 0):
// .x/.z accumulate into E, .y/.w into O.
#define INV_STEP(F0)                                                            \
  {                                                                             \
    _Pragma("unroll")                                                           \
    for (int r = 0; r < 8; ++r) {                                               \
      float4 av = *(const float4*)(&As[(w * 8 + r) * 64 + (F0)]);               \
      accE[r].x = fmaf(av.x, tg0.x, accE[r].x); accE[r].y = fmaf(av.x, tg0.y, accE[r].y); \
      accE[r].z = fmaf(av.x, tg0.z, accE[r].z); accE[r].w = fmaf(av.x, tg0.w, accE[r].w); \
      accO[r].x = fmaf(av.y, tg1.x, accO[r].x); accO[r].y = fmaf(av.y, tg1.y, accO[r].y); \
      accO[r].z = fmaf(av.y, tg1.z, accO[r].z); accO[r].w = fmaf(av.y, tg1.w, accO[r].w); \
      accE[r].x = fmaf(av.z, tg2.x, accE[r].x); accE[r].y = fmaf(av.z, tg2.y, accE[r].y); \
      accE[r].z = fmaf(av.z, tg2.z, accE[r].z); accE[r].w = fmaf(av.z, tg2.w, accE[r].w); \
      accO[r].x = fmaf(av.w, tg3.x, accO[r].x); accO[r].y = fmaf(av.w, tg3.y, accO[r].y); \
      accO[r].z = fmaf(av.w, tg3.z, accO[r].z); accO[r].w = fmaf(av.w, tg3.w, accO[r].w); \
    }                                                                           \
  }

  for (int fo = 0; fo < 15; ++fo) {
    int f0 = fo * 4;
    float4 n0 = *(const float4*)(trigt + (size_t)(f0 + 4) * NH + colb);
    float4 n1 = *(const float4*)(trigt + (size_t)(f0 + 5) * NH + colb);
    float4 n2 = *(const float4*)(trigt + (size_t)(f0 + 6) * NH + colb);
    float4 n3 = *(const float4*)(trigt + (size_t)(f0 + 7) * NH + colb);
    INV_STEP(f0);
    tg0 = n0; tg1 = n1; tg2 = n2; tg3 = n3;
  }
  INV_STEP(60);
#undef INV_STEP

  #pragma unroll
  for (int r = 0; r < 8; ++r) {
    int row = rowbase + w * 8 + r;
    float4 E = accE[r], O = accO[r];
    float4 s0 = make_float4(E.x + O.x, E.y + O.y, E.z + O.z, E.w + O.w);
    float4 s1 = make_float4(E.x - O.x, E.y - O.y, E.z - O.z, E.w - O.w);
    *(float4*)(out + (size_t)row * NN + colb)      = s0;
    *(float4*)(out + (size_t)row * NN + colb + NH) = s1;
  }
}

extern "C" void kernel_launch(void* const* d_in, const int* in_sizes, int n_in,
                              void* d_out, int out_size, void* d_ws, size_t ws_size,
                              hipStream_t stream) {
  const float* x     = (const float*)d_in[0];   // (32,64,8192)
  const float* w1r   = (const float*)d_in[1];   // (64,64,32)
  const float* w1i   = (const float*)d_in[2];   // (64,64,32)
  const float* gw    = (const float*)d_in[3];   // (64,64)
  const float* gamma = (const float*)d_in[4];   // (32,)
  const float* beta  = (const float*)d_in[5];   // (32,)
  float* out = (float*)d_out;                   // (32,64,8192)
  float* ws = (float*)d_ws;
  // split-K partials live in d_out (33.5 MB of its 64 MB) — fully overwritten by k_inv later
  float* part = (float*)d_out;

  hipLaunchKernelGGL(k_setup, dim3(1556), dim3(256), 0, stream, w1r, w1i, gw, ws);
  hipLaunchKernelGGL(k_fwd,   dim3(2560), dim3(256), 0, stream, x, ws, part, gamma, beta);
  hipLaunchKernelGGL(k_fred,  dim3(128),  dim3(256), 0, stream, part, ws);
  hipLaunchKernelGGL(k_gate,  dim3(1024), dim3(64),  0, stream, ws);
  hipLaunchKernelGGL(k_inv,   dim3(1024), dim3(256), 0, stream, ws, out);
}

// Round 6
// 177.959 us; speedup vs baseline: 1.2074x; 1.0019x over previous
//
#include <hip/hip_runtime.h>
#include <hip/hip_bf16.h>
#include <math.h>

// Problem constants
// B=32, C=64 (Cin==Cout), N=8192, modes F=32, L=20 segments, M=8 Chebyshev
#define NN    8192
#define NH    4096      // N/2 — folded DFT length
#define NROWS 2048      // B*C
#define FF    32
#define LM    160       // L*M

// Workspace layout (float offsets)
// TRIG layout (folded): [k4][f][4], k4=0..1023 (j=4*k4+e, j<4096):
//   ws[TRIG + (k4*64+f)*4 + e] = f<32 ? cos(2pi f (4k4+e)/N) : sin(2pi (f-32)(4k4+e)/N)
// TRIGT layout (folded): [f][j] j<4096 (rows 0..31 cos, 32..63 sin) — for k_inv
static constexpr int TRIG   = 0;         // 1024*64*4 = 262144 floats used
static constexpr int W1RT   = 524288;    // [f][i][o] 32*64*64
static constexpr int W1IT   = 655360;
static constexpr int GWT    = 786432;    // [i][o] 64*64
static constexpr int AR_    = 790528;    // [160][32]
static constexpr int AI_    = 795648;
static constexpr int WL_    = 800768;    // [160]
static constexpr int WR_    = 800928;
static constexpr int IL_    = 801088;    // int [160]
static constexpr int IR_    = 801248;
static constexpr int GN_    = 932480;    // [2048][32]
static constexpr int ARAI   = 998016;    // [2048][64]: [0..31]=cos coeff, [32..63]=sin coeff
static constexpr int TRIGT_ = 1129088;   // [64][4096] = 262144 floats used

#define PI_D 3.14159265358979323846

// ---------------- K1: all setup (trig tables | CFT tables | transposes) ----------------
__global__ __launch_bounds__(256) void k_setup(const float* __restrict__ w1r,
                                               const float* __restrict__ w1i,
                                               const float* __restrict__ gw,
                                               float* __restrict__ ws) {
  const int bid = blockIdx.x, tid = threadIdx.x;

  if (bid < 1024) {
    // ---- trig (folded, both layouts) ----
    int idx = bid * 256 + tid;                  // 0..262143
    int k4 = idx >> 8, f = (idx >> 2) & 63, e = idx & 3;
    int n = 4 * k4 + e;                          // 0..4095
    int fr = f & 31;
    int p = (fr * n) & (NN - 1);
    float ang = (float)p * (float)(2.0 * PI_D / (double)NN);
    float s, c;
    sincosf(ang, &s, &c);
    float v = (f < 32) ? c : s;
    ws[TRIG + idx] = v;
    ws[TRIGT_ + f * NH + n] = v;
    return;
  }

  if (bid < 1044) {
    // ---- CFT tables ----
    int t2 = (bid - 1024) * 256 + tid;
    if (t2 >= LM * FF) return;
    int j = t2 >> 5, f = t2 & 31;
    int l = j >> 3, m = j & 7;
    const double cheb[8] = {
      -0.98078528040323044913, -0.83146961230254523708,
      -0.55557023301960222474, -0.19509032201612826785,
       0.19509032201612826785,  0.55557023301960222474,
       0.83146961230254523708,  0.98078528040323044913 };

    double Wr = 0.0, Wi = 0.0;
    #pragma unroll
    for (int mm = 0; mm < 8; ++mm) {
      double c = cheb[mm];
      double T;
      if (m == 0) T = 1.0;
      else {
        double a = 1.0, b = c;
        for (int q = 1; q < m; ++q) { double t = 2.0 * c * b - a; a = b; b = t; }
        T = b;
      }
      double ang = c * (double)f * (PI_D * 0.05);
      Wr += T * cos(ang);
      Wi += T * (-sin(ang));
    }
    Wr *= 0.025; Wi *= 0.025;
    double phi = 2.0 * PI_D * ((double)l * 0.05) * (double)f;
    double cs = cos(phi), sn = sin(phi);
    ws[AR_ + j * FF + f] = (float)(Wr * cs + Wi * sn);
    ws[AI_ + j * FF + f] = (float)(-Wr * sn + Wi * cs);

    if (f == 0) {
      double v = (double)l * 0.05 + 0.025 * (cheb[m] + 1.0);
      int r = (int)(v * 8191.0);
      while ((double)r / 8191.0 < v) ++r;
      while (r > 0 && (double)(r - 1) / 8191.0 >= v) --r;
      if (r > 8191) r = 8191;
      int le = r - 1; if (le < 0) le = 0;
      double tl = (double)le / 8191.0, tr = (double)r / 8191.0;
      double den = (tr - tl == 0.0) ? 1.0 : (tr - tl);
      double wr = (v - tl) / den;
      ws[WL_ + j] = (float)(1.0 - wr);
      ws[WR_ + j] = (float)wr;
      ((int*)ws)[IL_ + j] = le;
      ((int*)ws)[IR_ + j] = r;
    }
    return;
  }

  // ---- transposes ----
  {
    int idx = (bid - 1044) * 256 + tid;         // 0..131071
    if (idx >= 32 * 64 * 64) return;
    int o = idx & 63, i = (idx >> 6) & 63, f = idx >> 12;
    ws[W1RT + (f * 64 + i) * 64 + o] = w1r[(i * 64 + o) * FF + f];
    ws[W1IT + (f * 64 + i) * 64 + o] = w1i[(i * 64 + o) * FF + f];
    if (idx < 4096) {
      ws[GWT + idx] = gw[(idx & 63) * 64 + (idx >> 6)];
    }
  }
}

// ---------------- K2: folded forward DFT (split-K 32) + CFT/LayerNorm ----------------
// blocks [0,1024): fwd. grid 32 rt x 32 jg; each block: 64 rows x 128 j in TWO
//   64-j chunks. Per chunk: x AND trig live in LDS (compute phase has ZERO global
//   loads -> no vmcnt stream mixing). Next chunk's x+trig prefetched into registers
//   BEFORE the current chunk's compute (async-stage split) so HBM latency hides
//   under ~2000 cyc of FMA. LDS 49.2 KB -> 3 blocks/CU.
//   part stored TRANSPOSED: part[jg][fslot][row] (fslot 0..31 cos, 32..63 sin)
//   so k_gate can reduce it with coalesced reads (k_fred eliminated).
// blocks [1024,1536): CFT magnitude + LayerNorm (independent; fills CU gaps).
__global__ __launch_bounds__(256, 3) void k_fwd(const float* __restrict__ x,
                                                float* __restrict__ ws,
                                                float* __restrict__ part,
                                                const float* __restrict__ gamma,
                                                const float* __restrict__ beta) {
  __shared__ __align__(16) float smem[8208 + 4096];  // u|pad|w (8208) + trig chunk (4096)
  const int bid = blockIdx.x;
  const int t = threadIdx.x;

  if (bid < 1024) {
    const int rt_ = bid >> 5, jg = bid & 31;
    const int w = t >> 6, lane = t & 63;
    const int half = lane >> 5, fl = lane & 31;
    const int rblock = rt_ * 64;
    const int jb0 = jg * 128;
    float* __restrict__ tbuf = smem + 8208;
    const float4* __restrict__ tg4src = (const float4*)(ws + TRIG) + (size_t)jg * 2048;

    float4 ra[4], rb[4], rt4[4];
    float accC[8], accS[8];
    #pragma unroll
    for (int r = 0; r < 8; ++r) { accC[r] = 0.f; accS[r] = 0.f; }

#define STAGE_LOAD(JB, C)                                                       \
    {                                                                           \
      _Pragma("unroll")                                                         \
      for (int p = 0; p < 4; ++p) {                                             \
        int idx = 256 * p + t;                                                  \
        int row = idx >> 4, cq = idx & 15;                                      \
        const float* __restrict__ xp =                                          \
            x + (size_t)(rblock + row) * NN + (JB) + cq * 4;                    \
        ra[p] = *(const float4*)xp;                                             \
        rb[p] = *(const float4*)(xp + NH);                                      \
        rt4[p] = tg4src[(C) * 1024 + 256 * p + t];                              \
      }                                                                         \
    }

#define STAGE_WRITE()                                                           \
    {                                                                           \
      _Pragma("unroll")                                                         \
      for (int p = 0; p < 4; ++p) {                                             \
        int idx = 256 * p + t;                                                  \
        int row = idx >> 4, cq = idx & 15;                                      \
        float4 a = ra[p], b = rb[p];                                            \
        *(float4*)(&smem[row * 64 + cq * 4]) =                                  \
            make_float4(a.x + b.x, a.y + b.y, a.z + b.z, a.w + b.w);            \
        *(float4*)(&smem[4112 + row * 64 + cq * 4]) =                           \
            make_float4(a.x - b.x, a.y - b.y, a.z - b.z, a.w - b.w);            \
        *(float4*)(&tbuf[(256 * p + t) * 4]) = rt4[p];                          \
      }                                                                         \
    }

    // per-lane fixed bases: parity picks u or w; trig cos at +it*256, sin at +128
    const float* __restrict__ xb = &smem[(fl & 1) * 4112 + (w * 16 + half * 8) * 64];
    const float* __restrict__ tb = &tbuf[fl * 4];

#define COMPUTE()                                                               \
    {                                                                           \
      _Pragma("unroll 8")                                                       \
      for (int it = 0; it < 16; ++it) {                                         \
        float4 tc = *(const float4*)(tb + it * 256);                            \
        float4 tn = *(const float4*)(tb + it * 256 + 128);                      \
        _Pragma("unroll")                                                       \
        for (int j = 0; j < 8; ++j) {                                           \
          float4 xv = *(const float4*)(xb + j * 64 + it * 4);                   \
          accC[j] = fmaf(xv.w, tc.w, fmaf(xv.z, tc.z,                           \
                    fmaf(xv.y, tc.y, fmaf(xv.x, tc.x, accC[j]))));              \
          accS[j] = fmaf(xv.w, tn.w, fmaf(xv.z, tn.z,                           \
                    fmaf(xv.y, tn.y, fmaf(xv.x, tn.x, accS[j]))));              \
        }                                                                       \
      }                                                                         \
    }

    STAGE_LOAD(jb0, 0);
    STAGE_WRITE();                 // one exposed waitcnt per block
    __syncthreads();
    STAGE_LOAD(jb0 + 64, 1);       // prefetch chunk 1 (in flight during compute)
    COMPUTE();                     // chunk 0: zero global loads
    __syncthreads();               // all waves done reading chunk 0
    STAGE_WRITE();                 // chunk 1 (loads completed under compute)
    __syncthreads();
    COMPUTE();                     // chunk 1

#undef STAGE_LOAD
#undef STAGE_WRITE
#undef COMPUTE

    // part[jg][fslot][row]: per lane 2x float4 (rows contiguous) per acc array
    float* __restrict__ pp = part + (size_t)jg * 131072 + (size_t)fl * 2048
                                  + rblock + w * 16 + half * 8;
    *(float4*)(pp)             = make_float4(accC[0], accC[1], accC[2], accC[3]);
    *(float4*)(pp + 4)         = make_float4(accC[4], accC[5], accC[6], accC[7]);
    *(float4*)(pp + 65536)     = make_float4(accS[0], accS[1], accS[2], accS[3]);
    *(float4*)(pp + 65536 + 4) = make_float4(accS[4], accS[5], accS[6], accS[7]);
    return;
  }

  // ---- CFT magnitude + LayerNorm ----
  {
    const int cb = bid - 1024;
    const int sub = t >> 6, li = t & 63;
    const int row = cb * 4 + sub;
    const float* __restrict__ xr = x + (size_t)row * NN;
    float (*seg)[LM] = (float (*)[LM])smem;
    #pragma unroll
    for (int g = 0; g < 3; ++g) {
      int j = li + 64 * g;
      if (j < LM) {
        int il = ((const int*)ws)[IL_ + j];
        int ir = ((const int*)ws)[IR_ + j];
        seg[sub][j] = ws[WL_ + j] * xr[il] + ws[WR_ + j] * xr[ir];
      }
    }
    __syncthreads();
    if (li < FF) {
      float re = 0.f, im = 0.f;
      #pragma unroll 8
      for (int j = 0; j < LM; ++j) {
        float sv = seg[sub][j];
        re = fmaf(sv, ws[AR_ + j * FF + li], re);
        im = fmaf(sv, ws[AI_ + j * FF + li], im);
      }
      float mag = sqrtf(re * re + im * im);
      float mu = mag;
      mu += __shfl_xor(mu, 1);  mu += __shfl_xor(mu, 2);  mu += __shfl_xor(mu, 4);
      mu += __shfl_xor(mu, 8);  mu += __shfl_xor(mu, 16);
      mu *= (1.0f / 32.0f);
      float d = mag - mu;
      float vv = d * d;
      vv += __shfl_xor(vv, 1);  vv += __shfl_xor(vv, 2);  vv += __shfl_xor(vv, 4);
      vv += __shfl_xor(vv, 8);  vv += __shfl_xor(vv, 16);
      vv *= (1.0f / 32.0f);
      float g = d / sqrtf(vv + 1e-5f) * gamma[li] + beta[li];
      ws[GN_ + row * FF + li] = g;
    }
  }
}

// ---------------- K3: gate (fused split-K reduce -> LN-gate -> channel mix) ----------------
// grid 256 = 32 b x 8 fgroups; 256 threads = 4 f-subgroups x 64 o.
// Reduces part[32][fslot][row] directly (coalesced: consecutive o = consecutive rows).
__global__ __launch_bounds__(256) void k_gate(const float* __restrict__ part,
                                              float* __restrict__ ws) {
  const int bidx = blockIdx.x;            // b*8 + fg
  const int b = bidx >> 3, fg = bidx & 7;
  const int sub = threadIdx.x >> 6, o = threadIdx.x & 63;
  const int f = fg * 4 + sub;
  __shared__ float gn[4][64], gr[4][64], gi[4][64];
  const int rowb = b * 64;
  const int row = rowb + o;

  // fused split-K reduction; rfft imag = -sum x sin
  float sc = 0.f, ss = 0.f;
  #pragma unroll 8
  for (int jg = 0; jg < 32; ++jg) {
    sc += part[(size_t)jg * 131072 + (size_t)f * 2048 + row];
    ss += part[(size_t)jg * 131072 + (size_t)(32 + f) * 2048 + row];
  }
  float xre = sc, xim = -ss;

  gn[sub][o] = ws[GN_ + row * FF + f];
  __syncthreads();
  float acc = 0.f;
  #pragma unroll 16
  for (int i = 0; i < 64; ++i)
    acc = fmaf(ws[GWT + i * 64 + o], gn[sub][i], acc);
  float gate = 1.0f / (1.0f + expf(-acc));
  gr[sub][o] = xre * gate;
  gi[sub][o] = xim * gate;
  __syncthreads();
  float Yr = 0.f, Yi = 0.f;
  const float* __restrict__ w1rt = ws + W1RT + f * 4096;
  const float* __restrict__ w1it = ws + W1IT + f * 4096;
  #pragma unroll 8
  for (int i = 0; i < 64; ++i) {
    float a = gr[sub][i], b2 = gi[sub][i];
    float wr = w1rt[i * 64 + o], wi = w1it[i * 64 + o];
    Yr = fmaf(a, wr, Yr); Yr = fmaf(-b2, wi, Yr);
    Yi = fmaf(a, wi, Yi); Yi = fmaf(b2, wr, Yi);
  }
  float* __restrict__ A = ws + ARAI + (size_t)row * 64;
  if (f == 0) {
    A[0]  = Yr * (1.0f / (float)NN);
    A[32] = 0.0f;
  } else {
    A[f]      = Yr * (2.0f / (float)NN);
    A[32 + f] = -Yi * (2.0f / (float)NN);
  }
}

// ---------------- K4: folded inverse (2048x64)@(64x4096) -> mirrored pair ----------------
// out[j] = E[j]+O[j], out[j+4096] = E[j]-O[j]; E/O = even/odd-f partial sums.
__global__ __launch_bounds__(256) void k_inv(const float* __restrict__ ws,
                                             float* __restrict__ out) {
  __shared__ __align__(16) float As[32 * 64];     // 8 KB
  const int blk = blockIdx.x;
  const int bb = blk >> 4, cc = blk & 15;
  const int t = threadIdx.x;
  const int w = t >> 6, lane = t & 63;
  const int rowbase = bb * 32;
  const float* __restrict__ trigt = ws + TRIGT_;
  const int colb = cc * 256 + lane * 4;           // 0..4092

  float4 tg0 = *(const float4*)(trigt + (size_t)0 * NH + colb);
  float4 tg1 = *(const float4*)(trigt + (size_t)1 * NH + colb);
  float4 tg2 = *(const float4*)(trigt + (size_t)2 * NH + colb);
  float4 tg3 = *(const float4*)(trigt + (size_t)3 * NH + colb);

  #pragma unroll
  for (int p = 0; p < 2; ++p) {
    int idx = t + 256 * p;
    int r = idx >> 4, q = idx & 15;
    *(float4*)(&As[r * 64 + q * 4]) =
        *(const float4*)(ws + ARAI + (size_t)(rowbase + r) * 64 + q * 4);
  }

  float4 accE[8], accO[8];
  #pragma unroll
  for (int r = 0; r < 8; ++r) {
    accE[r] = make_float4(0.f, 0.f, 0.f, 0.f);
    accO[r] = make_float4(0.f, 0.f, 0.f, 0.f);
  }

  __syncthreads();

// f-slots F0..F0+3 have parity even,odd,even,odd (F0 % 4 == 0):
// .x/.z accumulate into E, .y/.w into O.
#define INV_STEP(F0)                                                            \
  {                                                                             \
    _Pragma("unroll")                                                           \
    for (int r = 0; r < 8; ++r) {                                               \
      float4 av = *(const float4*)(&As[(w * 8 + r) * 64 + (F0)]);               \
      accE[r].x = fmaf(av.x, tg0.x, accE[r].x); accE[r].y = fmaf(av.x, tg0.y, accE[r].y); \
      accE[r].z = fmaf(av.x, tg0.z, accE[r].z); accE[r].w = fmaf(av.x, tg0.w, accE[r].w); \
      accO[r].x = fmaf(av.y, tg1.x, accO[r].x); accO[r].y = fmaf(av.y, tg1.y, accO[r].y); \
      accO[r].z = fmaf(av.y, tg1.z, accO[r].z); accO[r].w = fmaf(av.y, tg1.w, accO[r].w); \
      accE[r].x = fmaf(av.z, tg2.x, accE[r].x); accE[r].y = fmaf(av.z, tg2.y, accE[r].y); \
      accE[r].z = fmaf(av.z, tg2.z, accE[r].z); accE[r].w = fmaf(av.z, tg2.w, accE[r].w); \
      accO[r].x = fmaf(av.w, tg3.x, accO[r].x); accO[r].y = fmaf(av.w, tg3.y, accO[r].y); \
      accO[r].z = fmaf(av.w, tg3.z, accO[r].z); accO[r].w = fmaf(av.w, tg3.w, accO[r].w); \
    }                                                                           \
  }

  for (int fo = 0; fo < 15; ++fo) {
    int f0 = fo * 4;
    float4 n0 = *(const float4*)(trigt + (size_t)(f0 + 4) * NH + colb);
    float4 n1 = *(const float4*)(trigt + (size_t)(f0 + 5) * NH + colb);
    float4 n2 = *(const float4*)(trigt + (size_t)(f0 + 6) * NH + colb);
    float4 n3 = *(const float4*)(trigt + (size_t)(f0 + 7) * NH + colb);
    INV_STEP(f0);
    tg0 = n0; tg1 = n1; tg2 = n2; tg3 = n3;
  }
  INV_STEP(60);
#undef INV_STEP

  #pragma unroll
  for (int r = 0; r < 8; ++r) {
    int row = rowbase + w * 8 + r;
    float4 E = accE[r], O = accO[r];
    float4 s0 = make_float4(E.x + O.x, E.y + O.y, E.z + O.z, E.w + O.w);
    float4 s1 = make_float4(E.x - O.x, E.y - O.y, E.z - O.z, E.w - O.w);
    *(float4*)(out + (size_t)row * NN + colb)      = s0;
    *(float4*)(out + (size_t)row * NN + colb + NH) = s1;
  }
}

extern "C" void kernel_launch(void* const* d_in, const int* in_sizes, int n_in,
                              void* d_out, int out_size, void* d_ws, size_t ws_size,
                              hipStream_t stream) {
  const float* x     = (const float*)d_in[0];   // (32,64,8192)
  const float* w1r   = (const float*)d_in[1];   // (64,64,32)
  const float* w1i   = (const float*)d_in[2];   // (64,64,32)
  const float* gw    = (const float*)d_in[3];   // (64,64)
  const float* gamma = (const float*)d_in[4];   // (32,)
  const float* beta  = (const float*)d_in[5];   // (32,)
  float* out = (float*)d_out;                   // (32,64,8192)
  float* ws = (float*)d_ws;
  // split-K partials (16.8 MB) live in d_out — fully overwritten by k_inv later
  float* part = (float*)d_out;

  hipLaunchKernelGGL(k_setup, dim3(1556), dim3(256), 0, stream, w1r, w1i, gw, ws);
  hipLaunchKernelGGL(k_fwd,   dim3(1536), dim3(256), 0, stream, x, ws, part, gamma, beta);
  hipLaunchKernelGGL(k_gate,  dim3(256),  dim3(256), 0, stream, part, ws);
  hipLaunchKernelGGL(k_inv,   dim3(1024), dim3(256), 0, stream, ws, out);
}